// Round 2
// baseline (1735.028 us; speedup 1.0000x reference)
//
#include <hip/hip_runtime.h>
#include <cstdint>
#include <cstddef>

#define TSEQ  2048
#define CDIM  1024
#define NHEAD 8

// log2(0.96875)
#define LOG2GAMMA -0.045803689613325814f
// log2(10000)/32
#define ROPE_L2F   0.4152410118609203f

typedef __attribute__((ext_vector_type(8))) short  bf16x8;
typedef __attribute__((ext_vector_type(4))) float  f32x4;
typedef __attribute__((ext_vector_type(4))) unsigned short u16x4;
typedef __attribute__((ext_vector_type(8))) unsigned short u16x8;

typedef __attribute__((address_space(1))) void GASV;
typedef __attribute__((address_space(3))) void LASV;

__device__ __forceinline__ unsigned short f2bf(float x){
  unsigned int u = __float_as_uint(x);
  u += 0x7fffu + ((u >> 16) & 1u);          // round-to-nearest-even
  return (unsigned short)(u >> 16);
}

__device__ __forceinline__ void gld16(void* lds, const void* g){
  __builtin_amdgcn_global_load_lds((GASV*)g, (LASV*)lds, 16, 0, 0);
}

__device__ __forceinline__ f32x4 mfma16(bf16x8 a, bf16x8 b, f32x4 c){
  return __builtin_amdgcn_mfma_f32_16x16x32_bf16(a, b, c, 0, 0, 0);
}

// ---------------------------------------------------------------- X f32 -> bf16
__global__ void k_cvt_x(const float* __restrict__ X, unsigned short* __restrict__ Xb){
  const int i = (blockIdx.x * 256 + threadIdx.x) * 4;
  f32x4 v = *(const f32x4*)(X + i);
  u16x4 o;
  o[0]=f2bf(v[0]); o[1]=f2bf(v[1]); o[2]=f2bf(v[2]); o[3]=f2bf(v[3]);
  *(u16x4*)(Xb + i) = o;
}

// ------------------------------------- W f32 [k][n] -> bf16 transposed [n][k]
__global__ void k_cvt_w(const float* __restrict__ W0, const float* __restrict__ W1,
                        const float* __restrict__ W2, unsigned short* __restrict__ WbT){
  __shared__ float tile[64][65];
  const int bid = blockIdx.x;
  const int w = bid >> 11;           // 2048 blocks per weight matrix
  const int rem = bid & 2047;
  const int ktile = rem >> 7;        // 16 k-tiles of 64
  const int ntile = rem & 127;       // 128 n-tiles of 64
  const float* W = (w==0) ? W0 : (w==1) ? W1 : W2;
  const int k0 = ktile*64, n0 = ntile*64;
  const int tid = threadIdx.x;
  const int rr  = tid >> 4;
  const int cc4 = (tid & 15) * 4;
  #pragma unroll
  for (int it=0; it<4; ++it){
    int r = it*16 + rr;
    f32x4 v = *(const f32x4*)(W + (size_t)(k0 + r)*8192 + n0 + cc4);
    tile[r][cc4+0]=v[0]; tile[r][cc4+1]=v[1]; tile[r][cc4+2]=v[2]; tile[r][cc4+3]=v[3];
  }
  __syncthreads();
  #pragma unroll
  for (int it=0; it<4; ++it){
    int nn = it*16 + rr;
    u16x4 o;
    o[0]=f2bf(tile[cc4+0][nn]); o[1]=f2bf(tile[cc4+1][nn]);
    o[2]=f2bf(tile[cc4+2][nn]); o[3]=f2bf(tile[cc4+3][nn]);
    *(u16x4*)(WbT + ((size_t)w*8192 + n0 + nn)*1024 + k0 + cc4) = o;
  }
}

// ---------------------------------------------------------------- QKV GEMM
// C[m,n] = sum_k Xb[m,k] * WbT[n,k]; M=2048, N=24576, K=1024.
// 128x128 tile, BK=64 (128B LDS rows, XOR swizzle byte^=((byte>>7)&7)<<4).
// XCD swizzle: each XCD owns 2 bm-rows -> A L2-resident, B streams via L3.
// Epilogue: RoPE (Q,K; c<64) + SiLU, store Q/K as [h][t][c], V as [h][c][t].
__global__ __launch_bounds__(256) void k_gemm(
    const unsigned short* __restrict__ Xb, const unsigned short* __restrict__ WbT,
    unsigned short* __restrict__ Qo, unsigned short* __restrict__ Ko,
    unsigned short* __restrict__ Vo)
{
  __shared__ char smem[34816];              // 16K A | 16K B ; epilogue reuses 34K
  const int tid  = threadIdx.x;
  const int lane = tid & 63;
  const int wv   = tid >> 6;
  // bijective XCD chunking: 3072 blocks, 8 XCDs, 384 per XCD = 2 bm-rows each
  const int logical = (blockIdx.x & 7) * 384 + (blockIdx.x >> 3);
  const int bm = logical / 192, bn = logical % 192;
  const int m0 = bm * 128;
  const int n0 = bn * 128;
  const int w    = n0 >> 13;                // which weight matrix
  const int nw0  = n0 & 8191;
  const int h    = nw0 >> 10;
  const int cblk = nw0 & 1023;
  const char* Ag = (const char*)(Xb + (size_t)m0*1024);
  const char* Bg = (const char*)(WbT + ((size_t)w*8192 + nw0)*1024);
  const int wm = (wv >> 1) * 64, wn = (wv & 1) * 64;
  f32x4 acc[4][4] = {};

  // precompute swizzled LDS byte offsets (kt/kk-invariant; kk=1 -> ^64)
  int lbA[4], lbB[4];
  #pragma unroll
  for (int f=0; f<4; f++){
    int r  = wm + f*16 + (lane & 15);
    int lb = (r<<7) + ((lane>>4)<<4);
    lbA[f] = lb ^ (((lb>>7)&7)<<4);
    r  = wn + f*16 + (lane & 15);
    lb = (r<<7) + ((lane>>4)<<4);
    lbB[f] = (lb ^ (((lb>>7)&7)<<4)) + 16384;
  }
  // per-thread staging source offsets (swizzled), kt-invariant
  int srcRow[4], srcCol[4], dstOff[4];
  #pragma unroll
  for (int i=0;i<4;i++){
    int o = (i*256 + tid)*16;
    int u = o ^ (((o>>7)&7)<<4);
    srcRow[i] = u>>7; srcCol[i] = u&127;
    dstOff[i] = (i*256 + (tid & ~63))*16;
  }

  #pragma unroll 1
  for (int kt=0; kt<16; ++kt){
    __syncthreads();
    const int kbyte0 = kt*128;
    #pragma unroll
    for (int i=0;i<4;i++)                   // stage A: 128 rows x 128B
      gld16(smem + dstOff[i], Ag + (size_t)srcRow[i]*2048 + kbyte0 + srcCol[i]);
    #pragma unroll
    for (int i=0;i<4;i++)                   // stage B
      gld16(smem + 16384 + dstOff[i], Bg + (size_t)srcRow[i]*2048 + kbyte0 + srcCol[i]);
    __syncthreads();
    #pragma unroll
    for (int kk=0; kk<2; ++kk){
      const int kx = kk<<6;
      bf16x8 bfr[4];
      #pragma unroll
      for (int f=0; f<4; f++)
        bfr[f] = *(const bf16x8*)(smem + (lbB[f]^kx));
      #pragma unroll
      for (int fm=0; fm<4; fm++){
        bf16x8 a = *(const bf16x8*)(smem + (lbA[fm]^kx));
        #pragma unroll
        for (int fn=0; fn<4; fn++)
          acc[fm][fn] = mfma16(a, bfr[fn], acc[fm][fn]);
      }
    }
  }

  // ---- epilogue: RoPE on Q/K for c<64 (pairs are adjacent lanes: shfl_xor 1)
  if ((w < 2) && (cblk == 0) && (wn == 0)){
    #pragma unroll
    for (int fm=0; fm<4; fm++)
      #pragma unroll
      for (int fn=0; fn<4; fn++)
        #pragma unroll
        for (int r=0; r<4; r++){
          float x = acc[fm][fn][r];
          float p = __shfl_xor(x, 1);
          int c = fn*16 + (lane & 15);           // 0..63
          int t = m0 + wm + fm*16 + ((lane>>4)<<2) + r;
          float ang = (float)t * exp2f(-ROPE_L2F * (float)(c >> 1));
          float sn, cs; sincosf(ang, &sn, &cs);
          acc[fm][fn][r] = (c & 1) ? (x*cs + p*sn) : (x*cs - p*sn);
        }
  }
  __syncthreads();
  unsigned short* sm16 = (unsigned short*)smem;
  if (w < 2){
    #pragma unroll
    for (int fm=0; fm<4; fm++)
      #pragma unroll
      for (int fn=0; fn<4; fn++)
        #pragma unroll
        for (int r=0; r<4; r++){
          float x = acc[fm][fn][r];
          x = x / (1.f + __expf(-x));            // SiLU
          int rr2 = wm + fm*16 + ((lane>>4)<<2) + r;
          int cc2 = wn + fn*16 + (lane & 15);
          sm16[rr2*128 + cc2] = f2bf(x);
        }
    __syncthreads();
    unsigned short* dst = (w == 0 ? Qo : Ko);
    #pragma unroll
    for (int it=0; it<8; ++it){
      int rr2 = it*16 + (tid >> 4);
      int cc2 = (tid & 15) * 8;
      u16x8 v = *(const u16x8*)(sm16 + rr2*128 + cc2);
      *(u16x8*)(dst + ((size_t)h*TSEQ + m0 + rr2)*1024 + cblk + cc2) = v;
    }
  } else {
    // V: transpose to [h][c][t] via padded LDS tile (stride 136 elems = 272B)
    #pragma unroll
    for (int fm=0; fm<4; fm++)
      #pragma unroll
      for (int fn=0; fn<4; fn++)
        #pragma unroll
        for (int r=0; r<4; r++){
          float x = acc[fm][fn][r];
          x = x / (1.f + __expf(-x));
          int rr2 = wm + fm*16 + ((lane>>4)<<2) + r;
          int cc2 = wn + fn*16 + (lane & 15);
          sm16[cc2*136 + rr2] = f2bf(x);
        }
    __syncthreads();
    #pragma unroll
    for (int it=0; it<8; ++it){
      int nn = it*16 + (tid >> 4);
      int mm = (tid & 15) * 8;
      u16x8 v = *(const u16x8*)(sm16 + nn*136 + mm);
      *(u16x8*)(Vo + ((size_t)(h*1024 + cblk + nn))*TSEQ + m0 + mm) = v;
    }
  }
}

// ---------------------------------------------------------------- attention
// out_h[k,c] = sum_{q>=k, q-k<512} gamma^(q-k) * (K_k . Q_q) * V[q,c]
// block = (ktile of 64 rows, head). 512 threads / 8 waves.
__global__ __launch_bounds__(512,2) void k_attn(
    const unsigned short* __restrict__ Qb, const unsigned short* __restrict__ Kb,
    const unsigned short* __restrict__ Vt, float* __restrict__ outp)
{
  __shared__ char smem[40960];              // K 8K | Q 16K | S 16K
  char* Ksm = smem;
  char* Qsm = smem + 8192;
  char* Ssm = smem + 24576;
  const int tid = threadIdx.x, lane = tid & 63, wv = tid >> 6;
  const int h = blockIdx.x & 7, kt = blockIdx.x >> 3;   // head = bid%8 -> XCD locality
  const int k0 = kt * 64;
  const char* Kh = (const char*)(Kb + (size_t)h*TSEQ*1024);
  const char* Qh = (const char*)(Qb + (size_t)h*TSEQ*1024);
  const unsigned short* Vh = Vt + (size_t)h*1024*TSEQ;
  const int wm1 = (wv >> 2) * 32, wn1 = (wv & 3) * 32;  // phase-1 wave grid 2x4
  f32x4 acc2[4][8] = {};

  #pragma unroll 1
  for (int j=0; j<4; ++j){
    const int q0 = k0 + j*128;
    if (q0 >= TSEQ) break;
    // ---- phase 1: S[64][128] = K[k0..][:] @ Q[q0..][:]^T over c
    f32x4 accs[2][2] = {};
    #pragma unroll 1
    for (int ct=0; ct<16; ++ct){
      __syncthreads();
      {
        int o = tid*16;
        int u = o ^ (((o>>7)&7)<<4);
        gld16(Ksm + (tid & ~63)*16, Kh + (size_t)(k0 + (u>>7))*2048 + ct*128 + (u&127));
      }
      #pragma unroll
      for (int i=0;i<2;i++){
        int o = (i*512 + tid)*16;
        int u = o ^ (((o>>7)&7)<<4);
        int qr = q0 + (u>>7); if (qr > TSEQ-1) qr = TSEQ-1;   // clamp (masked later)
        gld16(Qsm + (i*512 + (tid & ~63))*16, Qh + (size_t)qr*2048 + ct*128 + (u&127));
      }
      __syncthreads();
      #pragma unroll
      for (int kk=0; kk<2; ++kk){
        bf16x8 a[2], b[2];
        #pragma unroll
        for (int f=0; f<2; f++){
          int r  = wm1 + f*16 + (lane & 15);
          int lb = (r<<7) + kk*64 + ((lane>>4)<<4);
          lb ^= ((lb>>7)&7)<<4;
          a[f] = *(const bf16x8*)(Ksm + lb);
        }
        #pragma unroll
        for (int f=0; f<2; f++){
          int r  = wn1 + f*16 + (lane & 15);
          int lb = (r<<7) + kk*64 + ((lane>>4)<<4);
          lb ^= ((lb>>7)&7)<<4;
          b[f] = *(const bf16x8*)(Qsm + lb);
        }
        accs[0][0] = mfma16(a[0], b[0], accs[0][0]);
        accs[0][1] = mfma16(a[0], b[1], accs[0][1]);
        accs[1][0] = mfma16(a[1], b[0], accs[1][0]);
        accs[1][1] = mfma16(a[1], b[1], accs[1][1]);
      }
    }
    // ---- decay mask + S -> bf16 LDS (rows 256B, swizzled)
    unsigned short* S16 = (unsigned short*)Ssm;
    #pragma unroll
    for (int fm=0; fm<2; fm++)
      #pragma unroll
      for (int fn=0; fn<2; fn++)
        #pragma unroll
        for (int r=0; r<4; r++){
          int kl = wm1 + fm*16 + ((lane>>4)<<2) + r;   // 0..63
          int ql = wn1 + fn*16 + (lane & 15);          // 0..127
          int dq = (q0 + ql) - (k0 + kl);
          float dfac = (dq >= 0 && (q0 + ql) < TSEQ) ? exp2f(LOG2GAMMA * (float)dq) : 0.f;
          float sv = accs[fm][fn][r] * dfac;
          int lb = (kl<<8) + (ql<<1);
          lb ^= ((lb>>8)&7)<<4;
          S16[lb>>1] = f2bf(sv);
        }
    __syncthreads();
    // ---- phase 2: acc2 += S[64][128] @ V[128][1024]; V B-frags direct from global Vt
    #pragma unroll
    for (int qs=0; qs<4; ++qs){
      bf16x8 bfr[8];
      #pragma unroll
      for (int f=0; f<8; f++){
        int c = wv*128 + f*16 + (lane & 15);
        int tt = q0 + qs*32 + ((lane>>4)<<3);
        if (tt > TSEQ-8) tt = TSEQ-8;                  // clamp (S=0 masks)
        bfr[f] = *(const bf16x8*)(Vh + (size_t)c*TSEQ + tt);
      }
      bf16x8 afr[4];
      #pragma unroll
      for (int f=0; f<4; f++){
        int m  = f*16 + (lane & 15);
        int lb = (m<<8) + ((qs*32 + ((lane>>4)<<3))<<1);
        lb ^= ((lb>>8)&7)<<4;
        afr[f] = *(const bf16x8*)(Ssm + lb);
      }
      #pragma unroll
      for (int fm=0; fm<4; fm++)
        #pragma unroll
        for (int fn=0; fn<8; fn++)
          acc2[fm][fn] = mfma16(afr[fm], bfr[fn], acc2[fm][fn]);
    }
    __syncthreads();
  }
  // ---- write per-head f32 partial [h][t][c]
  float* outh = outp + (size_t)h*TSEQ*1024;
  #pragma unroll
  for (int fm=0; fm<4; fm++)
    #pragma unroll
    for (int fn=0; fn<8; fn++)
      #pragma unroll
      for (int r=0; r<4; r++){
        int row = k0 + fm*16 + ((lane>>4)<<2) + r;
        int c   = wv*128 + fn*16 + (lane & 15);
        outh[(size_t)row*1024 + c] = acc2[fm][fn][r];
      }
}

// ---------------------------------------------------------------- head-sum + GroupNorm
__global__ void k_gn(const float* __restrict__ outp, const float* __restrict__ gnw,
                     const float* __restrict__ gnb, float* __restrict__ out)
{
  const int t = blockIdx.x;
  const int tid = threadIdx.x;       // 256
  const int c = tid * 4;
  f32x4 v = {0.f,0.f,0.f,0.f};
  #pragma unroll
  for (int p=0; p<8; p++){
    f32x4 u = *(const f32x4*)(outp + ((size_t)p*TSEQ + t)*1024 + c);
    v[0]+=u[0]; v[1]+=u[1]; v[2]+=u[2]; v[3]+=u[3];
  }
  float s  = v[0]+v[1]+v[2]+v[3];
  float s2 = v[0]*v[0]+v[1]*v[1]+v[2]*v[2]+v[3]*v[3];
  #pragma unroll
  for (int m=1; m<16; m<<=1){ s += __shfl_xor(s, m); s2 += __shfl_xor(s2, m); }
  float mean = s * (1.f/64.f);
  float var  = s2 * (1.f/64.f) - mean*mean;
  float rs   = rsqrtf(var + 1e-5f);
  f32x4 gw = *(const f32x4*)(gnw + c);
  f32x4 gb = *(const f32x4*)(gnb + c);
  f32x4 o;
  #pragma unroll
  for (int j2=0; j2<4; j2++) o[j2] = (v[j2]-mean)*rs*gw[j2] + gb[j2];
  *(f32x4*)(out + (size_t)t*1024 + c) = o;
}

// ---------------------------------------------------------------- launch
extern "C" void kernel_launch(void* const* d_in, const int* in_sizes, int n_in,
                              void* d_out, int out_size, void* d_ws, size_t ws_size,
                              hipStream_t stream)
{
  (void)in_sizes; (void)n_in; (void)out_size; (void)ws_size;
  const float* X   = (const float*)d_in[0];
  const float* W0  = (const float*)d_in[1];
  const float* W1  = (const float*)d_in[2];
  const float* W2  = (const float*)d_in[3];
  const float* gnw = (const float*)d_in[4];
  const float* gnb = (const float*)d_in[5];
  float* out = (float*)d_out;
  char* ws = (char*)d_ws;
  const size_t MB = 1024*1024;
  // Layout: [0,52MB): Xb(4MB)+WbT(48MB), later aliased by outp (64MB, written
  // only after k_gemm no longer needs Xb/WbT). Q @64MB, K @96MB, V @128MB.
  unsigned short* Xb  = (unsigned short*)(ws);
  unsigned short* WbT = (unsigned short*)(ws + 4*MB);
  float*          outp= (float*)(ws);                 // 64 MB, aliases Xb/WbT
  unsigned short* Qb  = (unsigned short*)(ws + 64*MB);
  unsigned short* Kb  = (unsigned short*)(ws + 96*MB);
  unsigned short* Vb  = (unsigned short*)(ws + 128*MB);

  k_cvt_x<<<2048, 256, 0, stream>>>(X, Xb);
  k_cvt_w<<<6144, 256, 0, stream>>>(W0, W1, W2, WbT);
  k_gemm <<<3072, 256, 0, stream>>>(Xb, WbT, Qb, Kb, Vb);
  k_attn <<<256,  512, 0, stream>>>(Qb, Kb, Vb, outp);
  k_gn   <<<2048, 256, 0, stream>>>(outp, gnw, gnb, out);
}

// Round 5
// 487.695 us; speedup vs baseline: 3.5576x; 3.5576x over previous
//
#include <hip/hip_runtime.h>
#include <cstdint>
#include <cstddef>

#define TSEQ  2048
#define CDIM  1024
#define NHEAD 8

// log2(0.96875)
#define LOG2GAMMA -0.045803689613325814f
// log2(10000)/32
#define ROPE_L2F   0.4152410118609203f

typedef __attribute__((ext_vector_type(8))) short  bf16x8;
typedef __attribute__((ext_vector_type(4))) float  f32x4;
typedef __attribute__((ext_vector_type(4))) unsigned short u16x4;
typedef __attribute__((ext_vector_type(8))) unsigned short u16x8;

typedef __attribute__((address_space(1))) void GASV;
typedef __attribute__((address_space(3))) void LASV;

__device__ __forceinline__ unsigned short f2bf(float x){
  unsigned int u = __float_as_uint(x);
  u += 0x7fffu + ((u >> 16) & 1u);          // round-to-nearest-even
  return (unsigned short)(u >> 16);
}

__device__ __forceinline__ void gld16(void* lds, const void* g){
  __builtin_amdgcn_global_load_lds((GASV*)g, (LASV*)lds, 16, 0, 0);
}

__device__ __forceinline__ f32x4 mfma16(bf16x8 a, bf16x8 b, f32x4 c){
  return __builtin_amdgcn_mfma_f32_16x16x32_bf16(a, b, c, 0, 0, 0);
}

// ---------------------------------------------------------------- X f32 -> bf16
__global__ void k_cvt_x(const float* __restrict__ X, unsigned short* __restrict__ Xb){
  const int i = (blockIdx.x * 256 + threadIdx.x) * 4;
  f32x4 v = *(const f32x4*)(X + i);
  u16x4 o;
  o[0]=f2bf(v[0]); o[1]=f2bf(v[1]); o[2]=f2bf(v[2]); o[3]=f2bf(v[3]);
  *(u16x4*)(Xb + i) = o;
}

// ------------------------------------- W f32 [k][n] -> bf16 transposed [n][k]
__global__ void k_cvt_w(const float* __restrict__ W0, const float* __restrict__ W1,
                        const float* __restrict__ W2, unsigned short* __restrict__ WbT){
  __shared__ float tile[64][65];
  const int bid = blockIdx.x;
  const int w = bid >> 11;           // 2048 blocks per weight matrix
  const int rem = bid & 2047;
  const int ktile = rem >> 7;        // 16 k-tiles of 64
  const int ntile = rem & 127;       // 128 n-tiles of 64
  const float* W = (w==0) ? W0 : (w==1) ? W1 : W2;
  const int k0 = ktile*64, n0 = ntile*64;
  const int tid = threadIdx.x;
  const int rr  = tid >> 4;
  const int cc4 = (tid & 15) * 4;
  #pragma unroll
  for (int it=0; it<4; ++it){
    int r = it*16 + rr;
    f32x4 v = *(const f32x4*)(W + (size_t)(k0 + r)*8192 + n0 + cc4);
    tile[r][cc4+0]=v[0]; tile[r][cc4+1]=v[1]; tile[r][cc4+2]=v[2]; tile[r][cc4+3]=v[3];
  }
  __syncthreads();
  #pragma unroll
  for (int it=0; it<4; ++it){
    int nn = it*16 + rr;
    u16x4 o;
    o[0]=f2bf(tile[cc4+0][nn]); o[1]=f2bf(tile[cc4+1][nn]);
    o[2]=f2bf(tile[cc4+2][nn]); o[3]=f2bf(tile[cc4+3][nn]);
    *(u16x4*)(WbT + ((size_t)w*8192 + n0 + nn)*1024 + k0 + cc4) = o;
  }
}

// ---------------------------------------------------------------- QKV GEMM
// C[m,n] = sum_k Xb[m,k] * WbT[n,k]; M=2048, N=24576, K=1024.
// 128x128 tile, BK=64, 512 threads / 8 waves, wave subtile 64x32.
// Spill-proof: acc = f32x4[4][2] (32 regs/thread).
__global__ __launch_bounds__(512,1) void k_gemm(
    const unsigned short* __restrict__ Xb, const unsigned short* __restrict__ WbT,
    unsigned short* __restrict__ Qo, unsigned short* __restrict__ Ko,
    unsigned short* __restrict__ Vo)
{
  __shared__ char smem[34816];              // 16K A | 16K B ; epilogue reuses 34K
  const int tid  = threadIdx.x;
  const int lane = tid & 63;
  const int wv   = tid >> 6;
  const int bid  = blockIdx.x;
  const int bm = bid / 192, bn = bid % 192;
  const int m0 = bm * 128;
  const int n0 = bn * 128;
  const int w    = n0 >> 13;                // which weight matrix
  const int nw0  = n0 & 8191;
  const int h    = nw0 >> 10;
  const int cblk = nw0 & 1023;
  const char* Ag = (const char*)(Xb + (size_t)m0*1024);
  const char* Bg = (const char*)(WbT + ((size_t)w*8192 + nw0)*1024);
  const int wm = (wv >> 2) * 64;            // 0 or 64
  const int wn = (wv & 3) * 32;             // 0,32,64,96
  f32x4 acc[4][2] = {};

  // staging offsets (kt-invariant): 2 chunks of A, 2 of B per thread
  int srcA[2], srcB[2], dstOff[2];
  #pragma unroll
  for (int i=0;i<2;i++){
    int o = (i*512 + tid)*16;
    int u = o ^ (((o>>7)&7)<<4);
    srcA[i] = (u>>7)*2048 + (u&127);
    srcB[i] = srcA[i];
    dstOff[i] = (i*512 + (tid & ~63))*16;
  }

  #pragma unroll 1
  for (int kt=0; kt<16; ++kt){
    __syncthreads();
    const int kbyte0 = kt*128;
    #pragma unroll
    for (int i=0;i<2;i++)
      gld16(smem + dstOff[i], Ag + (size_t)srcA[i] + kbyte0);
    #pragma unroll
    for (int i=0;i<2;i++)
      gld16(smem + 16384 + dstOff[i], Bg + (size_t)srcB[i] + kbyte0);
    __syncthreads();
    #pragma unroll
    for (int kk=0; kk<2; ++kk){
      const int kcol = kk*64 + ((lane>>4)<<4);
      bf16x8 bfr[2];
      #pragma unroll
      for (int f=0; f<2; f++){
        int r  = wn + f*16 + (lane & 15);
        int lb = (r<<7) + kcol;
        lb ^= ((lb>>7)&7)<<4;
        bfr[f] = *(const bf16x8*)(smem + 16384 + lb);
      }
      #pragma unroll
      for (int fm=0; fm<4; fm++){
        int r  = wm + fm*16 + (lane & 15);
        int lb = (r<<7) + kcol;
        lb ^= ((lb>>7)&7)<<4;
        bf16x8 a = *(const bf16x8*)(smem + lb);
        acc[fm][0] = mfma16(a, bfr[0], acc[fm][0]);
        acc[fm][1] = mfma16(a, bfr[1], acc[fm][1]);
      }
    }
  }

  // ---- epilogue: RoPE on Q/K for c<64 (pairs are adjacent lanes: shfl_xor 1)
  if ((w < 2) && (cblk == 0) && (wn < 64)){
    #pragma unroll
    for (int fm=0; fm<4; fm++)
      #pragma unroll
      for (int fn=0; fn<2; fn++)
        #pragma unroll
        for (int r=0; r<4; r++){
          float x = acc[fm][fn][r];
          float p = __shfl_xor(x, 1);
          int c = wn + fn*16 + (lane & 15);      // 0..63
          int t = m0 + wm + fm*16 + ((lane>>4)<<2) + r;
          float ang = (float)t * exp2f(-ROPE_L2F * (float)(c >> 1));
          float sn, cs; sincosf(ang, &sn, &cs);
          acc[fm][fn][r] = (c & 1) ? (x*cs + p*sn) : (x*cs - p*sn);
        }
  }
  __syncthreads();
  unsigned short* sm16 = (unsigned short*)smem;
  if (w < 2){
    #pragma unroll
    for (int fm=0; fm<4; fm++)
      #pragma unroll
      for (int fn=0; fn<2; fn++)
        #pragma unroll
        for (int r=0; r<4; r++){
          float x = acc[fm][fn][r];
          x = x / (1.f + __expf(-x));            // SiLU
          int rr2 = wm + fm*16 + ((lane>>4)<<2) + r;
          int cc2 = wn + fn*16 + (lane & 15);
          sm16[rr2*128 + cc2] = f2bf(x);
        }
    __syncthreads();
    unsigned short* dst = (w == 0 ? Qo : Ko);
    #pragma unroll
    for (int it=0; it<4; ++it){
      int rr2 = it*32 + (tid >> 4);
      int cc2 = (tid & 15) * 8;
      u16x8 v = *(const u16x8*)(sm16 + rr2*128 + cc2);
      *(u16x8*)(dst + ((size_t)h*TSEQ + m0 + rr2)*1024 + cblk + cc2) = v;
    }
  } else {
    // V: transpose to [h][c][t] via padded LDS tile (stride 136 elems = 272B)
    #pragma unroll
    for (int fm=0; fm<4; fm++)
      #pragma unroll
      for (int fn=0; fn<2; fn++)
        #pragma unroll
        for (int r=0; r<4; r++){
          float x = acc[fm][fn][r];
          x = x / (1.f + __expf(-x));
          int rr2 = wm + fm*16 + ((lane>>4)<<2) + r;
          int cc2 = wn + fn*16 + (lane & 15);
          sm16[cc2*136 + rr2] = f2bf(x);
        }
    __syncthreads();
    #pragma unroll
    for (int it=0; it<4; ++it){
      int nn = it*32 + (tid >> 4);
      int mm = (tid & 15) * 8;
      u16x8 v = *(const u16x8*)(sm16 + nn*136 + mm);
      *(u16x8*)(Vo + ((size_t)(h*1024 + cblk + nn))*TSEQ + m0 + mm) = v;
    }
  }
}

// ---------------------------------------------------------------- attention
// out_h[k,c] = sum_{q>=k} gamma^(q-k) * (K_k . Q_q) * V[q,c]
// block = (ktile of 64 rows, head). 512 threads / 8 waves.
__global__ __launch_bounds__(512,1) void k_attn(
    const unsigned short* __restrict__ Qb, const unsigned short* __restrict__ Kb,
    const unsigned short* __restrict__ Vt, float* __restrict__ outp)
{
  __shared__ char smem[40960];              // K 8K | Q 16K | S 16K
  char* Ksm = smem;
  char* Qsm = smem + 8192;
  char* Ssm = smem + 24576;
  const int tid = threadIdx.x, lane = tid & 63, wv = tid >> 6;
  const int h = blockIdx.x & 7, kt = blockIdx.x >> 3;   // head = bid%8 -> XCD locality
  const int k0 = kt * 64;
  const char* Kh = (const char*)(Kb + (size_t)h*TSEQ*1024);
  const char* Qh = (const char*)(Qb + (size_t)h*TSEQ*1024);
  const unsigned short* Vh = Vt + (size_t)h*1024*TSEQ;
  const int wm1 = (wv >> 2) * 32, wn1 = (wv & 3) * 32;  // phase-1 wave grid 2x4
  f32x4 acc2[4][8] = {};

  #pragma unroll 1
  for (int j=0; j<4; ++j){
    const int q0 = k0 + j*128;
    if (q0 >= TSEQ) break;
    // ---- phase 1: S[64][128] = K[k0..][:] @ Q[q0..][:]^T over c
    f32x4 accs[2][2] = {};
    #pragma unroll 1
    for (int ct=0; ct<16; ++ct){
      __syncthreads();
      {
        int o = tid*16;
        int u = o ^ (((o>>7)&7)<<4);
        gld16(Ksm + (tid & ~63)*16, Kh + (size_t)(k0 + (u>>7))*2048 + ct*128 + (u&127));
      }
      #pragma unroll
      for (int i=0;i<2;i++){
        int o = (i*512 + tid)*16;
        int u = o ^ (((o>>7)&7)<<4);
        int qr = q0 + (u>>7); if (qr > TSEQ-1) qr = TSEQ-1;   // clamp (masked later)
        gld16(Qsm + (i*512 + (tid & ~63))*16, Qh + (size_t)qr*2048 + ct*128 + (u&127));
      }
      __syncthreads();
      #pragma unroll
      for (int kk=0; kk<2; ++kk){
        bf16x8 a[2], b[2];
        #pragma unroll
        for (int f=0; f<2; f++){
          int r  = wm1 + f*16 + (lane & 15);
          int lb = (r<<7) + kk*64 + ((lane>>4)<<4);
          lb ^= ((lb>>7)&7)<<4;
          a[f] = *(const bf16x8*)(Ksm + lb);
        }
        #pragma unroll
        for (int f=0; f<2; f++){
          int r  = wn1 + f*16 + (lane & 15);
          int lb = (r<<7) + kk*64 + ((lane>>4)<<4);
          lb ^= ((lb>>7)&7)<<4;
          b[f] = *(const bf16x8*)(Qsm + lb);
        }
        accs[0][0] = mfma16(a[0], b[0], accs[0][0]);
        accs[0][1] = mfma16(a[0], b[1], accs[0][1]);
        accs[1][0] = mfma16(a[1], b[0], accs[1][0]);
        accs[1][1] = mfma16(a[1], b[1], accs[1][1]);
      }
    }
    // ---- decay mask + S -> bf16 LDS (rows 256B, swizzled)
    unsigned short* S16 = (unsigned short*)Ssm;
    #pragma unroll
    for (int fm=0; fm<2; fm++)
      #pragma unroll
      for (int fn=0; fn<2; fn++)
        #pragma unroll
        for (int r=0; r<4; r++){
          int kl = wm1 + fm*16 + ((lane>>4)<<2) + r;   // 0..63
          int ql = wn1 + fn*16 + (lane & 15);          // 0..127
          int dq = (q0 + ql) - (k0 + kl);
          float dfac = (dq >= 0 && (q0 + ql) < TSEQ) ? exp2f(LOG2GAMMA * (float)dq) : 0.f;
          float sv = accs[fm][fn][r] * dfac;
          int lb = (kl<<8) + (ql<<1);
          lb ^= ((lb>>8)&7)<<4;
          S16[lb>>1] = f2bf(sv);
        }
    __syncthreads();
    // ---- phase 2: acc2 += S[64][128] @ V[128][1024]; V B-frags direct from global Vt
    #pragma unroll
    for (int qs=0; qs<4; ++qs){
      bf16x8 bfr[8];
      #pragma unroll
      for (int f=0; f<8; f++){
        int c = wv*128 + f*16 + (lane & 15);
        int tt = q0 + qs*32 + ((lane>>4)<<3);
        if (tt > TSEQ-8) tt = TSEQ-8;                  // clamp (S=0 masks)
        bfr[f] = *(const bf16x8*)(Vh + (size_t)c*TSEQ + tt);
      }
      bf16x8 afr[4];
      #pragma unroll
      for (int f=0; f<4; f++){
        int m  = f*16 + (lane & 15);
        int lb = (m<<8) + ((qs*32 + ((lane>>4)<<3))<<1);
        lb ^= ((lb>>8)&7)<<4;
        afr[f] = *(const bf16x8*)(Ssm + lb);
      }
      #pragma unroll
      for (int fm=0; fm<4; fm++)
        #pragma unroll
        for (int fn=0; fn<8; fn++)
          acc2[fm][fn] = mfma16(afr[fm], bfr[fn], acc2[fm][fn]);
    }
    __syncthreads();
  }
  // ---- write per-head f32 partial [h][t][c]
  float* outh = outp + (size_t)h*TSEQ*1024;
  #pragma unroll
  for (int fm=0; fm<4; fm++)
    #pragma unroll
    for (int fn=0; fn<8; fn++)
      #pragma unroll
      for (int r=0; r<4; r++){
        int row = k0 + fm*16 + ((lane>>4)<<2) + r;
        int c   = wv*128 + fn*16 + (lane & 15);
        outh[(size_t)row*1024 + c] = acc2[fm][fn][r];
      }
}

// ---------------------------------------------------------------- head-sum + GroupNorm
__global__ void k_gn(const float* __restrict__ outp, const float* __restrict__ gnw,
                     const float* __restrict__ gnb, float* __restrict__ out)
{
  const int t = blockIdx.x;
  const int tid = threadIdx.x;       // 256
  const int c = tid * 4;
  f32x4 v = {0.f,0.f,0.f,0.f};
  #pragma unroll
  for (int p=0; p<8; p++){
    f32x4 u = *(const f32x4*)(outp + ((size_t)p*TSEQ + t)*1024 + c);
    v[0]+=u[0]; v[1]+=u[1]; v[2]+=u[2]; v[3]+=u[3];
  }
  float s  = v[0]+v[1]+v[2]+v[3];
  float s2 = v[0]*v[0]+v[1]*v[1]+v[2]*v[2]+v[3]*v[3];
  #pragma unroll
  for (int m=1; m<16; m<<=1){ s += __shfl_xor(s, m); s2 += __shfl_xor(s2, m); }
  float mean = s * (1.f/64.f);
  float var  = s2 * (1.f/64.f) - mean*mean;
  float rs   = rsqrtf(var + 1e-5f);
  f32x4 gw = *(const f32x4*)(gnw + c);
  f32x4 gb = *(const f32x4*)(gnb + c);
  f32x4 o;
  #pragma unroll
  for (int j2=0; j2<4; j2++) o[j2] = (v[j2]-mean)*rs*gw[j2] + gb[j2];
  *(f32x4*)(out + (size_t)t*1024 + c) = o;
}

// ---------------------------------------------------------------- launch
extern "C" void kernel_launch(void* const* d_in, const int* in_sizes, int n_in,
                              void* d_out, int out_size, void* d_ws, size_t ws_size,
                              hipStream_t stream)
{
  (void)in_sizes; (void)n_in; (void)out_size; (void)ws_size;
  const float* X   = (const float*)d_in[0];
  const float* W0  = (const float*)d_in[1];
  const float* W1  = (const float*)d_in[2];
  const float* W2  = (const float*)d_in[3];
  const float* gnw = (const float*)d_in[4];
  const float* gnb = (const float*)d_in[5];
  float* out = (float*)d_out;
  char* ws = (char*)d_ws;
  const size_t MB = 1024*1024;
  // Layout: [0,52MB): Xb(4MB)+WbT(48MB), later aliased by outp (64MB, written
  // only after k_gemm no longer needs Xb/WbT). Q @64MB, K @96MB, V @128MB.
  unsigned short* Xb  = (unsigned short*)(ws);
  unsigned short* WbT = (unsigned short*)(ws + 4*MB);
  float*          outp= (float*)(ws);                 // 64 MB, aliases Xb/WbT
  unsigned short* Qb  = (unsigned short*)(ws + 64*MB);
  unsigned short* Kb  = (unsigned short*)(ws + 96*MB);
  unsigned short* Vb  = (unsigned short*)(ws + 128*MB);

  k_cvt_x<<<2048, 256, 0, stream>>>(X, Xb);
  k_cvt_w<<<6144, 256, 0, stream>>>(W0, W1, W2, WbT);
  k_gemm <<<3072, 512, 0, stream>>>(Xb, WbT, Qb, Kb, Vb);
  k_attn <<<256,  512, 0, stream>>>(Qb, Kb, Vb, outp);
  k_gn   <<<2048, 256, 0, stream>>>(outp, gnw, gnb, out);
}